// Round 10
// baseline (455.411 us; speedup 1.0000x reference)
//
#include <hip/hip_runtime.h>
#include <hip/hip_bf16.h>
#include <hip/hip_cooperative_groups.h>
#include <math.h>

namespace cg = cooperative_groups;

typedef short bf16x8 __attribute__((ext_vector_type(8)));
typedef float f32x4 __attribute__((ext_vector_type(4)));

#define N0v 120000
#define N1v 12000
#define N2v 1024
#define F_INv 602
#define KPADv 608
#define HCv 64
#define NCLSv 41
#define NEGv 0.2f

__device__ __forceinline__ float b2f(unsigned short u) {
  return __uint_as_float(((unsigned int)u) << 16);
}
__device__ __forceinline__ unsigned short f2b(float f) {
  unsigned int u = __float_as_uint(f);
  u += 0x7fffu + ((u >> 16) & 1u);
  return (unsigned short)(u >> 16);
}
__device__ __forceinline__ unsigned int pk2(float lo, float hi) {
  __hip_bfloat162 h = __float22bfloat162_rn(make_float2(lo, hi));
  unsigned int u;
  __builtin_memcpy(&u, &h, 4);
  return u;
}
__device__ __forceinline__ float leaky(float v) {
  return v > 0.f ? v : NEGv * v;
}

// ---------------- prep: W1 transpose+convert, zero deg arrays ----------------
__global__ void k_prep(const float* __restrict__ W1, unsigned short* __restrict__ Wt,
                       int* __restrict__ deg1, int* __restrict__ deg2) {
  int idx = blockIdx.x * 256 + threadIdx.x;
  if (idx < HCv * KPADv) {
    int n = idx / KPADv, k = idx % KPADv;
    Wt[idx] = (k < F_INv) ? f2b(W1[k * HCv + n]) : (unsigned short)0;
  }
  if (idx < N1v) deg1[idx] = 0;
  if (idx < N2v) deg2[idx] = 0;
}

// ---------------- GEMM (r4 core, ~69us) + fused edge counting ----------------
__global__ __launch_bounds__(512, 4) void k_gemm1(const float* __restrict__ x,
                                                  const unsigned short* __restrict__ Wt,
                                                  unsigned short* __restrict__ H,
                                                  float* __restrict__ as1,
                                                  float* __restrict__ ad1,
                                                  const float* __restrict__ att_s,
                                                  const float* __restrict__ att_d,
                                                  const int* __restrict__ dst1, int E1,
                                                  int* __restrict__ deg1,
                                                  const int* __restrict__ dst2, int E2,
                                                  int* __restrict__ deg2) {
  __shared__ unsigned short Bs[64][328];
  __shared__ float sAtt[128];
  const int tid = threadIdx.x;
  const int wave = tid >> 6, lane = tid & 63;
  const int c15 = lane & 15, kseg = lane >> 4;
  const int block_row = blockIdx.x * 128;
  const int myrow = block_row + wave * 16 + c15;
  const float* rowp = x + (size_t)min(myrow, N0v - 1) * F_INv;

  if (tid < 128) sAtt[tid] = (tid < 64) ? att_s[tid] : att_d[tid - 64];

  auto stage = [&](int kofs, int nc8) {
    int chunks = 64 * nc8;
    for (int i = tid; i < chunks; i += 512) {
      int rr = i / nc8, cc = (i % nc8) * 8;
      *reinterpret_cast<uint4*>(&Bs[rr][cc]) =
          *reinterpret_cast<const uint4*>(Wt + (size_t)rr * KPADv + kofs + cc);
    }
  };

  f32x4 acc[4];
#pragma unroll
  for (int n = 0; n < 4; ++n) acc[n] = (f32x4){0.f, 0.f, 0.f, 0.f};

  float cur[8], nxt[8];
  auto loadA = [&](int kt, float (&f)[8]) {
    const int kb = kt * 32 + kseg * 8;
    const float* p = rowp + kb;
    if (kb + 8 <= F_INv) {
#pragma unroll
      for (int q = 0; q < 4; ++q) {
        float2 t = *reinterpret_cast<const float2*>(p + 2 * q);
        f[2 * q] = t.x;
        f[2 * q + 1] = t.y;
      }
    } else {
      float2 t = *reinterpret_cast<const float2*>(p);
      f[0] = t.x;
      f[1] = t.y;
#pragma unroll
      for (int q = 2; q < 8; ++q) f[q] = 0.f;
    }
  };
  auto compute = [&](int kt) {
    union {
      unsigned int u[4];
      bf16x8 v;
    } af;
#pragma unroll
    for (int q = 0; q < 4; ++q) af.u[q] = pk2(cur[2 * q], cur[2 * q + 1]);
    const int kk = (kt < 10 ? kt * 32 : kt * 32 - 320) + kseg * 8;
#pragma unroll
    for (int n = 0; n < 4; ++n) {
      bf16x8 b = *reinterpret_cast<const bf16x8*>(&Bs[n * 16 + c15][kk]);
      acc[n] = __builtin_amdgcn_mfma_f32_16x16x32_bf16(af.v, b, acc[n], 0, 0, 0);
    }
  };

  stage(0, 40);
  loadA(0, cur);
  {  // fused degree count (deg zeroed in k_prep)
    int e = blockIdx.x * 512 + tid;
    if (e < E1) atomicAdd(&deg1[dst1[e]], 1);
    if (e < E2) atomicAdd(&deg2[dst2[e]], 1);
  }
  __syncthreads();
#pragma unroll
  for (int kt = 0; kt < 10; ++kt) {
    loadA(kt + 1, nxt);
    compute(kt);
#pragma unroll
    for (int q = 0; q < 8; ++q) cur[q] = nxt[q];
  }
  __syncthreads();
  stage(320, 36);
  __syncthreads();
#pragma unroll
  for (int kt = 10; kt < 19; ++kt) {
    if (kt < 18) loadA(kt + 1, nxt);
    compute(kt);
    if (kt < 18) {
#pragma unroll
      for (int q = 0; q < 8; ++q) cur[q] = nxt[q];
    }
  }

  float attS[4], attD[4];
#pragma unroll
  for (int n = 0; n < 4; ++n) {
    attS[n] = sAtt[n * 16 + c15];
    attD[n] = sAtt[64 + n * 16 + c15];
  }
#pragma unroll
  for (int j = 0; j < 4; ++j) {
    int row = block_row + wave * 16 + kseg * 4 + j;
    bool rok = row < N0v;
#pragma unroll
    for (int n = 0; n < 4; ++n) {
      if (rok) H[(size_t)row * HCv + n * 16 + c15] = f2b(acc[n][j]);
      float ps = acc[n][j] * attS[n];
      float pd = acc[n][j] * attD[n];
      ps += __shfl_xor(ps, 1, 64);
      ps += __shfl_xor(ps, 2, 64);
      ps += __shfl_xor(ps, 4, 64);
      pd += __shfl_xor(pd, 1, 64);
      pd += __shfl_xor(pd, 2, 64);
      pd += __shfl_xor(pd, 4, 64);
      if (rok && ((c15 & 7) == 0)) {
        int hd = n * 2 + (c15 >> 3);
        as1[(size_t)row * 8 + hd] = ps;
        if (row < N1v) ad1[(size_t)row * 8 + hd] = pd;
      }
    }
  }
}

// ---------------- shared device bodies ----------------
__device__ void scan_seq(const int* __restrict__ deg, int* __restrict__ rs,
                         int* __restrict__ cur, int n) {
  __shared__ int ws[4];
  const int t = threadIdx.x, lane = t & 63, wid = t >> 6;
  const int chunk = (n + 255) >> 8;
  const int lo = t * chunk, hi = min(n, lo + chunk);
  int tot = 0;
  for (int i = lo; i < hi; ++i) tot += deg[i];
  int s = tot;
#pragma unroll
  for (int off = 1; off < 64; off <<= 1) {
    int u = __shfl_up(s, off, 64);
    if (lane >= off) s += u;
  }
  if (lane == 63) ws[wid] = s;
  __syncthreads();
  int woff = 0;
#pragma unroll
  for (int j = 0; j < 3; ++j)
    if (wid > j) woff += ws[j];
  int run = woff + s - tot;
  for (int i = lo; i < hi; ++i) {
    rs[i] = run;
    cur[i] = run;
    run += deg[i];
  }
  if (t == 255) rs[n] = run;
}

__device__ __forceinline__ void attn1_body(int d, int lane, const int* rs1, const int* es1,
                                           const float* as1, const float* ad1,
                                           const unsigned short* H, const float* b1,
                                           const float* w, const float* vs, const float* vd,
                                           float* g, float* as2, float* ad2) {
  const int h = lane >> 3;
  const int lc = (lane < NCLSv) ? lane : 0;
  const int beg = rs1[d], end = rs1[d + 1];
  const float adh = ad1[(size_t)d * 8 + h];
  const float a_self = leaky(as1[(size_t)d * 8 + h] + adh);

  float m0 = a_self, m1 = -1e30f, m2 = -1e30f, m3 = -1e30f;
  int p = beg;
  for (; p + 4 <= end; p += 4) {
    int s0 = es1[p], s1 = es1[p + 1], s2 = es1[p + 2], s3 = es1[p + 3];
    m0 = fmaxf(m0, leaky(as1[(size_t)s0 * 8 + h] + adh));
    m1 = fmaxf(m1, leaky(as1[(size_t)s1 * 8 + h] + adh));
    m2 = fmaxf(m2, leaky(as1[(size_t)s2 * 8 + h] + adh));
    m3 = fmaxf(m3, leaky(as1[(size_t)s3 * 8 + h] + adh));
  }
  for (; p < end; ++p) m1 = fmaxf(m1, leaky(as1[(size_t)es1[p] * 8 + h] + adh));
  const float m = fmaxf(fmaxf(m0, m1), fmaxf(m2, m3));

  float ss0 = __expf(a_self - m), ss1 = 0.f, ss2 = 0.f, ss3 = 0.f;
  float ac0 = ss0 * b2f(H[(size_t)d * HCv + lane]), ac1 = 0.f, ac2 = 0.f, ac3 = 0.f;
  for (p = beg; p + 4 <= end; p += 4) {
    int s0 = es1[p], s1 = es1[p + 1], s2 = es1[p + 2], s3 = es1[p + 3];
    float e0 = __expf(leaky(as1[(size_t)s0 * 8 + h] + adh) - m);
    float e1 = __expf(leaky(as1[(size_t)s1 * 8 + h] + adh) - m);
    float e2 = __expf(leaky(as1[(size_t)s2 * 8 + h] + adh) - m);
    float e3 = __expf(leaky(as1[(size_t)s3 * 8 + h] + adh) - m);
    ac0 += e0 * b2f(H[(size_t)s0 * HCv + lane]);
    ac1 += e1 * b2f(H[(size_t)s1 * HCv + lane]);
    ac2 += e2 * b2f(H[(size_t)s2 * HCv + lane]);
    ac3 += e3 * b2f(H[(size_t)s3 * HCv + lane]);
    ss0 += e0;
    ss1 += e1;
    ss2 += e2;
    ss3 += e3;
  }
  for (; p < end; ++p) {
    int s = es1[p];
    float e = __expf(leaky(as1[(size_t)s * 8 + h] + adh) - m);
    ss1 += e;
    ac1 += e * b2f(H[(size_t)s * HCv + lane]);
  }
  const float ssum = (ss0 + ss1) + (ss2 + ss3);
  const float acc = (ac0 + ac1) + (ac2 + ac3);
  float o = acc / ssum + b1[lane];
  o = o > 0.f ? o : expm1f(o);  // ELU; h1 row stays in registers

  float gc = 0.f;
#pragma unroll
  for (int k = 0; k < HCv; ++k) {
    float bc = __shfl(o, k, 64);
    gc += bc * w[k * NCLSv + lc];
  }
  if (lane < NCLSv) g[(size_t)d * NCLSv + lane] = gc;
  float sa = (lane < NCLSv) ? gc * vs[lane] : 0.f;
  float da = (lane < NCLSv) ? gc * vd[lane] : 0.f;
#pragma unroll
  for (int off = 32; off >= 1; off >>= 1) {
    sa += __shfl_xor(sa, off, 64);
    da += __shfl_xor(da, off, 64);
  }
  if (lane == 0) {
    as2[d] = sa;
    ad2[d] = da;
  }
}

__device__ __forceinline__ void attn2_body(int d, int lane, const int* rs2, const int* es2,
                                           const float* as2, const float* ad2, const float* g,
                                           const float* b2, float* out) {
  int beg = rs2[d], end = rs2[d + 1];
  float ad = ad2[d];
  float a_self = leaky(as2[d] + ad);
  float m = a_self;
  for (int p = beg; p < end; ++p) m = fmaxf(m, leaky(as2[es2[p]] + ad));
  float ssum, acc;
  {
    float e = __expf(a_self - m);
    ssum = e;
    acc = (lane < NCLSv) ? e * g[(size_t)d * NCLSv + lane] : 0.f;
  }
  for (int p = beg; p < end; ++p) {
    int s = es2[p];
    float e = __expf(leaky(as2[s] + ad) - m);
    ssum += e;
    if (lane < NCLSv) acc += e * g[(size_t)s * NCLSv + lane];
  }
  float logit = acc / ssum + ((lane < NCLSv) ? b2[lane] : 0.f);
  float v = (lane < NCLSv) ? logit : -INFINITY;
  float mx = v;
#pragma unroll
  for (int off = 32; off >= 1; off >>= 1) mx = fmaxf(mx, __shfl_xor(mx, off, 64));
  float p = (lane < NCLSv) ? __expf(v - mx) : 0.f;
  float sum = p;
#pragma unroll
  for (int off = 32; off >= 1; off >>= 1) sum += __shfl_xor(sum, off, 64);
  if (lane < NCLSv) out[(size_t)d * NCLSv + lane] = v - mx - logf(sum);
}

// ---------------- cooperative tail ----------------
__global__ __launch_bounds__(256, 4) void k_tail(
    const int* __restrict__ src1, const int* __restrict__ dst1, int E1,
    const int* __restrict__ deg1, int* __restrict__ rs1, int* __restrict__ cur1,
    int* __restrict__ es1,
    const int* __restrict__ src2, const int* __restrict__ dst2, int E2,
    const int* __restrict__ deg2, int* __restrict__ rs2, int* __restrict__ cur2,
    int* __restrict__ es2,
    const float* __restrict__ as1, const float* __restrict__ ad1,
    const unsigned short* __restrict__ H, const float* __restrict__ b1,
    const float* __restrict__ W2, const float* __restrict__ avs, const float* __restrict__ avd,
    float* __restrict__ g, float* __restrict__ as2, float* __restrict__ ad2,
    const float* __restrict__ b2, float* __restrict__ out) {
  cg::grid_group grid = cg::this_grid();
  __shared__ float w[HCv * NCLSv];
  __shared__ float vs[NCLSv], vd[NCLSv];
  const int tid = threadIdx.x;
  const int gid = blockIdx.x * 256 + tid;
  const int gsz = gridDim.x * 256;
  const int lane = tid & 63;
  const int gwave = blockIdx.x * 4 + (tid >> 6);
  const int nwv = gridDim.x * 4;

  for (int i = tid; i < HCv * NCLSv; i += 256) w[i] = W2[i];
  if (tid < NCLSv) {
    vs[tid] = avs[tid];
    vd[tid] = avd[tid];
  }

  if (blockIdx.x == 0)
    scan_seq(deg1, rs1, cur1, N1v);
  else if (blockIdx.x == 1)
    scan_seq(deg2, rs2, cur2, N2v);
  grid.sync();
  for (int e = gid; e < E1; e += gsz) {
    int p = atomicAdd(&cur1[dst1[e]], 1);
    es1[p] = src1[e];
  }
  for (int e = gid; e < E2; e += gsz) {
    int p = atomicAdd(&cur2[dst2[e]], 1);
    es2[p] = src2[e];
  }
  grid.sync();
  for (int d = gwave; d < N1v; d += nwv)
    attn1_body(d, lane, rs1, es1, as1, ad1, H, b1, w, vs, vd, g, as2, ad2);
  grid.sync();
  for (int d = gwave; d < N2v; d += nwv)
    attn2_body(d, lane, rs2, es2, as2, ad2, g, b2, out);
}

// ---------------- fallback standalone kernels (r8 structure) ----------------
__global__ __launch_bounds__(256) void k_scan2x(const int* __restrict__ deg1, int* __restrict__ rs1,
                                                int* __restrict__ cur1,
                                                const int* __restrict__ deg2, int* __restrict__ rs2,
                                                int* __restrict__ cur2) {
  if (blockIdx.x == 0)
    scan_seq(deg1, rs1, cur1, N1v);
  else
    scan_seq(deg2, rs2, cur2, N2v);
}

__global__ void k_scatter2x(const int* __restrict__ src1, const int* __restrict__ dst1, int E1,
                            int* __restrict__ cur1, int* __restrict__ es1,
                            const int* __restrict__ src2, const int* __restrict__ dst2, int E2,
                            int* __restrict__ cur2, int* __restrict__ es2) {
  int e = blockIdx.x * 256 + threadIdx.x;
  if (e < E1) {
    int p = atomicAdd(&cur1[dst1[e]], 1);
    es1[p] = src1[e];
  }
  if (e < E2) {
    int p = atomicAdd(&cur2[dst2[e]], 1);
    es2[p] = src2[e];
  }
}

__global__ __launch_bounds__(256) void k_attn1f(const float* __restrict__ as1,
                                                const float* __restrict__ ad1,
                                                const int* __restrict__ rs,
                                                const int* __restrict__ esrc,
                                                const unsigned short* __restrict__ H,
                                                const float* __restrict__ b1,
                                                const float* __restrict__ W2,
                                                const float* __restrict__ avs,
                                                const float* __restrict__ avd,
                                                float* __restrict__ g,
                                                float* __restrict__ as2,
                                                float* __restrict__ ad2) {
  __shared__ float w[HCv * NCLSv];
  __shared__ float vs[NCLSv], vd[NCLSv];
  const int tid = threadIdx.x;
  for (int i = tid; i < HCv * NCLSv; i += 256) w[i] = W2[i];
  if (tid < NCLSv) {
    vs[tid] = avs[tid];
    vd[tid] = avd[tid];
  }
  __syncthreads();
  const int d = blockIdx.x * 4 + (tid >> 6);
  if (d >= N1v) return;
  attn1_body(d, tid & 63, rs, esrc, as1, ad1, H, b1, w, vs, vd, g, as2, ad2);
}

__global__ __launch_bounds__(256) void k_attn2(const float* __restrict__ as2,
                                               const float* __restrict__ ad2,
                                               const int* __restrict__ rs,
                                               const int* __restrict__ esrc,
                                               const float* __restrict__ g,
                                               const float* __restrict__ b2,
                                               float* __restrict__ out) {
  int d = blockIdx.x * 4 + (threadIdx.x >> 6);
  if (d >= N2v) return;
  attn2_body(d, threadIdx.x & 63, rs, esrc, as2, ad2, g, b2, out);
}

// ---------------- host launch ----------------
extern "C" void kernel_launch(void* const* d_in, const int* in_sizes, int n_in,
                              void* d_out, int out_size, void* d_ws, size_t ws_size,
                              hipStream_t stream) {
  const float* x = (const float*)d_in[0];
  const int* ei1 = (const int*)d_in[1];
  const int* ei2 = (const int*)d_in[2];
  const float* W1 = (const float*)d_in[5];
  const float* att_src1 = (const float*)d_in[6];
  const float* att_dst1 = (const float*)d_in[7];
  const float* b1 = (const float*)d_in[8];
  const float* W2 = (const float*)d_in[9];
  const float* att_src2 = (const float*)d_in[10];
  const float* att_dst2 = (const float*)d_in[11];
  const float* b2 = (const float*)d_in[12];
  float* outp = (float*)d_out;

  int E1 = in_sizes[1] / 2;
  int E2 = in_sizes[2] / 2;
  const int* src1 = ei1;
  const int* dst1 = ei1 + E1;
  const int* src2 = ei2;
  const int* dst2 = ei2 + E2;

  char* w = (char*)d_ws;
  size_t off = 0;
  auto alloc = [&](size_t bytes) {
    void* p = w + off;
    off += (bytes + 255) & ~(size_t)255;
    return p;
  };
  unsigned short* Wt  = (unsigned short*)alloc((size_t)HCv * KPADv * 2);
  unsigned short* H   = (unsigned short*)alloc((size_t)N0v * HCv * 2);
  float* as1 = (float*)alloc((size_t)N0v * 8 * 4);
  float* ad1 = (float*)alloc((size_t)N1v * 8 * 4);
  int* deg1  = (int*)alloc((size_t)N1v * 4);
  int* rs1   = (int*)alloc((size_t)(N1v + 1) * 4);
  int* cur1  = (int*)alloc((size_t)N1v * 4);
  int* es1   = (int*)alloc((size_t)E1 * 4);
  float* g   = (float*)alloc((size_t)N1v * NCLSv * 4);
  float* as2 = (float*)alloc((size_t)N1v * 4);
  float* ad2 = (float*)alloc((size_t)N1v * 4);
  int* deg2  = (int*)alloc((size_t)N2v * 4);
  int* rs2   = (int*)alloc((size_t)(N2v + 1) * 4);
  int* cur2  = (int*)alloc((size_t)N2v * 4);
  int* es2   = (int*)alloc((size_t)E2 * 4);
  (void)ws_size; (void)n_in; (void)out_size;

  k_prep<<<(HCv * KPADv + 255) / 256, 256, 0, stream>>>(W1, Wt, deg1, deg2);
  k_gemm1<<<(N0v + 127) / 128, 512, 0, stream>>>(x, Wt, H, as1, ad1, att_src1, att_dst1,
                                                 dst1, E1, deg1, dst2, E2, deg2);

  // cooperative tail at occupancy-legal grid; fall back to separate kernels on any failure
  bool coop_done = false;
  {
    int dev = 0;
    if (hipGetDevice(&dev) == hipSuccess) {
      int numCU = 0, blocksPerCU = 0;
      if (hipDeviceGetAttribute(&numCU, hipDeviceAttributeMultiprocessorCount, dev) == hipSuccess &&
          hipOccupancyMaxActiveBlocksPerMultiprocessor(&blocksPerCU, k_tail, 256, 0) == hipSuccess &&
          numCU > 0 && blocksPerCU > 0) {
        int gridsz = blocksPerCU * numCU;
        if (gridsz >= 2) {
          void* args[] = {
              (void*)&src1, (void*)&dst1, (void*)&E1,
              (void*)&deg1, (void*)&rs1, (void*)&cur1, (void*)&es1,
              (void*)&src2, (void*)&dst2, (void*)&E2,
              (void*)&deg2, (void*)&rs2, (void*)&cur2, (void*)&es2,
              (void*)&as1, (void*)&ad1, (void*)&H, (void*)&b1,
              (void*)&W2, (void*)&att_src2, (void*)&att_dst2,
              (void*)&g, (void*)&as2, (void*)&ad2, (void*)&b2, (void*)&outp};
          if (hipLaunchCooperativeKernel((const void*)k_tail, dim3(gridsz), dim3(256), args, 0,
                                         stream) == hipSuccess)
            coop_done = true;
        }
      }
    }
  }
  if (!coop_done) {
    k_scan2x<<<2, 256, 0, stream>>>(deg1, rs1, cur1, deg2, rs2, cur2);
    k_scatter2x<<<(E1 + 255) / 256, 256, 0, stream>>>(src1, dst1, E1, cur1, es1,
                                                      src2, dst2, E2, cur2, es2);
    k_attn1f<<<(N1v + 3) / 4, 256, 0, stream>>>(as1, ad1, rs1, es1, H, b1,
                                                W2, att_src2, att_dst2, g, as2, ad2);
    k_attn2<<<N2v / 4, 256, 0, stream>>>(as2, ad2, rs2, es2, g, b2, outp);
  }
}

// Round 11
// 179.054 us; speedup vs baseline: 2.5434x; 2.5434x over previous
//
#include <hip/hip_runtime.h>
#include <hip/hip_bf16.h>
#include <math.h>

typedef short bf16x8 __attribute__((ext_vector_type(8)));
typedef float f32x4 __attribute__((ext_vector_type(4)));

#define N0v 120000
#define N1v 12000
#define N2v 1024
#define F_INv 602
#define KPADv 608
#define HCv 64
#define NCLSv 41
#define NEGv 0.2f

__device__ __forceinline__ float b2f(unsigned short u) {
  return __uint_as_float(((unsigned int)u) << 16);
}
__device__ __forceinline__ unsigned short f2b(float f) {
  unsigned int u = __float_as_uint(f);
  u += 0x7fffu + ((u >> 16) & 1u);
  return (unsigned short)(u >> 16);
}
__device__ __forceinline__ unsigned int pk2(float lo, float hi) {
  __hip_bfloat162 h = __float22bfloat162_rn(make_float2(lo, hi));
  unsigned int u;
  __builtin_memcpy(&u, &h, 4);
  return u;
}
__device__ __forceinline__ float leaky(float v) {
  return v > 0.f ? v : NEGv * v;
}

// ---------------- prep: W1 transpose+convert, zero deg arrays ----------------
__global__ void k_prep(const float* __restrict__ W1, unsigned short* __restrict__ Wt,
                       int* __restrict__ deg1, int* __restrict__ deg2) {
  int idx = blockIdx.x * 256 + threadIdx.x;
  if (idx < HCv * KPADv) {
    int n = idx / KPADv, k = idx % KPADv;
    Wt[idx] = (k < F_INv) ? f2b(W1[k * HCv + n]) : (unsigned short)0;
  }
  if (idx < N1v) deg1[idx] = 0;
  if (idx < N2v) deg2[idx] = 0;
}

// ---------------- GEMM: depth-2 A prefetch (3 rotating reg buffers) + fused count ----------------
__global__ __launch_bounds__(512, 4) void k_gemm1(const float* __restrict__ x,
                                                  const unsigned short* __restrict__ Wt,
                                                  unsigned short* __restrict__ H,
                                                  float* __restrict__ as1,
                                                  float* __restrict__ ad1,
                                                  const float* __restrict__ att_s,
                                                  const float* __restrict__ att_d,
                                                  const int* __restrict__ dst1, int E1,
                                                  int* __restrict__ deg1,
                                                  const int* __restrict__ dst2, int E2,
                                                  int* __restrict__ deg2) {
  __shared__ unsigned short Bs[64][328];
  __shared__ float sAtt[128];
  const int tid = threadIdx.x;
  const int wave = tid >> 6, lane = tid & 63;
  const int c15 = lane & 15, kseg = lane >> 4;
  const int block_row = blockIdx.x * 128;
  const int myrow = block_row + wave * 16 + c15;
  const float* rowp = x + (size_t)min(myrow, N0v - 1) * F_INv;

  if (tid < 128) sAtt[tid] = (tid < 64) ? att_s[tid] : att_d[tid - 64];

  auto stage = [&](int kofs, int nc8) {
    int chunks = 64 * nc8;
    for (int i = tid; i < chunks; i += 512) {
      int rr = i / nc8, cc = (i % nc8) * 8;
      *reinterpret_cast<uint4*>(&Bs[rr][cc]) =
          *reinterpret_cast<const uint4*>(Wt + (size_t)rr * KPADv + kofs + cc);
    }
  };

  f32x4 acc[4];
#pragma unroll
  for (int n = 0; n < 4; ++n) acc[n] = (f32x4){0.f, 0.f, 0.f, 0.f};

  // 3 rotating A-tile buffers; static selection (kt compile-time in unrolled loops)
  float tA[8], tB[8], tC[8];
  auto bufref = [&](int i) -> float(&)[8] {
    return (i % 3 == 0) ? tA : ((i % 3 == 1) ? tB : tC);
  };
  auto loadA = [&](int kt, float (&f)[8]) {
    const int kb = kt * 32 + kseg * 8;
    const float* p = rowp + kb;
    if (kb + 8 <= F_INv) {
#pragma unroll
      for (int q = 0; q < 4; ++q) {
        float2 t = *reinterpret_cast<const float2*>(p + 2 * q);
        f[2 * q] = t.x;
        f[2 * q + 1] = t.y;
      }
    } else {  // kt=18, kseg=3: k=600..607 -> load 2, zero 6 (B pad is 0 there)
      float2 t = *reinterpret_cast<const float2*>(p);
      f[0] = t.x;
      f[1] = t.y;
#pragma unroll
      for (int q = 2; q < 8; ++q) f[q] = 0.f;
    }
  };
  auto compute = [&](int kt, const float (&f)[8]) {
    union {
      unsigned int u[4];
      bf16x8 v;
    } af;
#pragma unroll
    for (int q = 0; q < 4; ++q) af.u[q] = pk2(f[2 * q], f[2 * q + 1]);
    const int kk = (kt < 10 ? kt * 32 : kt * 32 - 320) + kseg * 8;
#pragma unroll
    for (int n = 0; n < 4; ++n) {
      bf16x8 b = *reinterpret_cast<const bf16x8*>(&Bs[n * 16 + c15][kk]);
      acc[n] = __builtin_amdgcn_mfma_f32_16x16x32_bf16(af.v, b, acc[n], 0, 0, 0);
    }
  };

  stage(0, 40);       // B half0: k 0..319
  loadA(0, tA);
  loadA(1, tB);
  {  // fused degree count (deg zeroed in k_prep; scan next dispatch)
    int e = blockIdx.x * 512 + tid;
    if (e < E1) atomicAdd(&deg1[dst1[e]], 1);
    if (e < E2) atomicAdd(&deg2[dst2[e]], 1);
  }
  __syncthreads();
#pragma unroll
  for (int kt = 0; kt < 10; ++kt) {
    if (kt + 2 < 19) loadA(kt + 2, bufref(kt + 2));
    compute(kt, bufref(kt));
  }
  __syncthreads();
  stage(320, 36);     // B half1: k 320..607
  __syncthreads();
#pragma unroll
  for (int kt = 10; kt < 19; ++kt) {
    if (kt + 2 < 19) loadA(kt + 2, bufref(kt + 2));
    compute(kt, bufref(kt));
  }

  float attS[4], attD[4];
#pragma unroll
  for (int n = 0; n < 4; ++n) {
    attS[n] = sAtt[n * 16 + c15];
    attD[n] = sAtt[64 + n * 16 + c15];
  }
#pragma unroll
  for (int j = 0; j < 4; ++j) {
    int row = block_row + wave * 16 + kseg * 4 + j;
    bool rok = row < N0v;
#pragma unroll
    for (int n = 0; n < 4; ++n) {
      if (rok) H[(size_t)row * HCv + n * 16 + c15] = f2b(acc[n][j]);
      float ps = acc[n][j] * attS[n];
      float pd = acc[n][j] * attD[n];
      ps += __shfl_xor(ps, 1, 64);
      ps += __shfl_xor(ps, 2, 64);
      ps += __shfl_xor(ps, 4, 64);
      pd += __shfl_xor(pd, 1, 64);
      pd += __shfl_xor(pd, 2, 64);
      pd += __shfl_xor(pd, 4, 64);
      if (rok && ((c15 & 7) == 0)) {
        int hd = n * 2 + (c15 >> 3);
        as1[(size_t)row * 8 + hd] = ps;
        if (row < N1v) ad1[(size_t)row * 8 + hd] = pd;
      }
    }
  }
}

// ---------------- scan (2 blocks, 1024 threads) ----------------
template <int ELT>
__device__ __forceinline__ void scan_body(const int* __restrict__ deg, int* __restrict__ rs,
                                          int* __restrict__ cur, int n) {
  __shared__ int wsum[16];
  const int t = threadIdx.x, lane = t & 63, wid = t >> 6;
  int vals[ELT];
  int tot = 0;
#pragma unroll
  for (int e = 0; e < ELT; ++e) {
    int i = t * ELT + e;
    int v = (i < n) ? deg[i] : 0;
    vals[e] = v;
    tot += v;
  }
  int s = tot;
#pragma unroll
  for (int off = 1; off < 64; off <<= 1) {
    int u = __shfl_up(s, off, 64);
    if (lane >= off) s += u;
  }
  if (lane == 63) wsum[wid] = s;
  __syncthreads();
  if (t < 16) {
    int w = wsum[t];
#pragma unroll
    for (int off = 1; off < 16; off <<= 1) {
      int u = __shfl_up(w, off, 64);
      if (t >= off) w += u;
    }
    wsum[t] = w;
  }
  __syncthreads();
  int woff = (wid == 0) ? 0 : wsum[wid - 1];
  int run = woff + s - tot;
#pragma unroll
  for (int e = 0; e < ELT; ++e) {
    int i = t * ELT + e;
    if (i < n) {
      rs[i] = run;
      cur[i] = run;
    }
    run += vals[e];
  }
  if (t == 1023) rs[n] = run;
}

__global__ __launch_bounds__(1024) void k_scan2x(const int* __restrict__ deg1, int* __restrict__ rs1,
                                                 int* __restrict__ cur1, int n1,
                                                 const int* __restrict__ deg2, int* __restrict__ rs2,
                                                 int* __restrict__ cur2, int n2) {
  if (blockIdx.x == 0)
    scan_body<12>(deg1, rs1, cur1, n1);
  else
    scan_body<12>(deg2, rs2, cur2, n2);
}

__global__ void k_scatter2x(const int* __restrict__ src1, const int* __restrict__ dst1, int E1,
                            int* __restrict__ cur1, int* __restrict__ es1,
                            const int* __restrict__ src2, const int* __restrict__ dst2, int E2,
                            int* __restrict__ cur2, int* __restrict__ es2) {
  int e = blockIdx.x * 256 + threadIdx.x;
  if (e < E1) {
    int p = atomicAdd(&cur1[dst1[e]], 1);
    es1[p] = src1[e];
  }
  if (e < E2) {
    int p = atomicAdd(&cur2[dst2[e]], 1);
    es2[p] = src2[e];
  }
}

// ---------------- attn1 + ELU + l2feat fused: wave per dst node, two-pass 4-way ----------------
__global__ __launch_bounds__(256) void k_attn1f(const float* __restrict__ as1,
                                                const float* __restrict__ ad1,
                                                const int* __restrict__ rs,
                                                const int* __restrict__ esrc,
                                                const unsigned short* __restrict__ H,
                                                const float* __restrict__ b1,
                                                const float* __restrict__ W2,
                                                const float* __restrict__ avs,
                                                const float* __restrict__ avd,
                                                float* __restrict__ g,
                                                float* __restrict__ as2,
                                                float* __restrict__ ad2) {
  __shared__ float w[HCv * NCLSv];
  __shared__ float vs[NCLSv], vd[NCLSv];
  const int tid = threadIdx.x;
  for (int i = tid; i < HCv * NCLSv; i += 256) w[i] = W2[i];
  if (tid < NCLSv) {
    vs[tid] = avs[tid];
    vd[tid] = avd[tid];
  }
  __syncthreads();
  const int lane = tid & 63;
  const int d = blockIdx.x * 4 + (tid >> 6);
  if (d >= N1v) return;
  const int h = lane >> 3;
  const int beg = rs[d], end = rs[d + 1];
  const float adh = ad1[(size_t)d * 8 + h];
  const float a_self = leaky(as1[(size_t)d * 8 + h] + adh);

  float m0 = a_self, m1 = -1e30f, m2 = -1e30f, m3 = -1e30f;
  int p = beg;
  for (; p + 4 <= end; p += 4) {
    int s0 = esrc[p], s1 = esrc[p + 1], s2 = esrc[p + 2], s3 = esrc[p + 3];
    m0 = fmaxf(m0, leaky(as1[(size_t)s0 * 8 + h] + adh));
    m1 = fmaxf(m1, leaky(as1[(size_t)s1 * 8 + h] + adh));
    m2 = fmaxf(m2, leaky(as1[(size_t)s2 * 8 + h] + adh));
    m3 = fmaxf(m3, leaky(as1[(size_t)s3 * 8 + h] + adh));
  }
  for (; p < end; ++p) m1 = fmaxf(m1, leaky(as1[(size_t)esrc[p] * 8 + h] + adh));
  const float m = fmaxf(fmaxf(m0, m1), fmaxf(m2, m3));

  float ss0 = __expf(a_self - m), ss1 = 0.f, ss2 = 0.f, ss3 = 0.f;
  float ac0 = ss0 * b2f(H[(size_t)d * HCv + lane]), ac1 = 0.f, ac2 = 0.f, ac3 = 0.f;
  for (p = beg; p + 4 <= end; p += 4) {
    int s0 = esrc[p], s1 = esrc[p + 1], s2 = esrc[p + 2], s3 = esrc[p + 3];
    float e0 = __expf(leaky(as1[(size_t)s0 * 8 + h] + adh) - m);
    float e1 = __expf(leaky(as1[(size_t)s1 * 8 + h] + adh) - m);
    float e2 = __expf(leaky(as1[(size_t)s2 * 8 + h] + adh) - m);
    float e3 = __expf(leaky(as1[(size_t)s3 * 8 + h] + adh) - m);
    ac0 += e0 * b2f(H[(size_t)s0 * HCv + lane]);
    ac1 += e1 * b2f(H[(size_t)s1 * HCv + lane]);
    ac2 += e2 * b2f(H[(size_t)s2 * HCv + lane]);
    ac3 += e3 * b2f(H[(size_t)s3 * HCv + lane]);
    ss0 += e0;
    ss1 += e1;
    ss2 += e2;
    ss3 += e3;
  }
  for (; p < end; ++p) {
    int s = esrc[p];
    float e = __expf(leaky(as1[(size_t)s * 8 + h] + adh) - m);
    ss1 += e;
    ac1 += e * b2f(H[(size_t)s * HCv + lane]);
  }
  const float ssum = (ss0 + ss1) + (ss2 + ss3);
  const float acc = (ac0 + ac1) + (ac2 + ac3);
  float o = acc / ssum + b1[lane];
  o = o > 0.f ? o : expm1f(o);  // ELU; h1 row stays in registers

  const int lc = (lane < NCLSv) ? lane : 0;
  float gc = 0.f;
#pragma unroll
  for (int k = 0; k < HCv; ++k) {
    float bc = __shfl(o, k, 64);
    gc += bc * w[k * NCLSv + lc];
  }
  if (lane < NCLSv) g[(size_t)d * NCLSv + lane] = gc;
  float sa = (lane < NCLSv) ? gc * vs[lane] : 0.f;
  float da = (lane < NCLSv) ? gc * vd[lane] : 0.f;
#pragma unroll
  for (int off = 32; off >= 1; off >>= 1) {
    sa += __shfl_xor(sa, off, 64);
    da += __shfl_xor(da, off, 64);
  }
  if (lane == 0) {
    as2[d] = sa;
    ad2[d] = da;
  }
}

// ---------------- layer-2 attention + log_softmax ----------------
__global__ __launch_bounds__(256) void k_attn2(const float* __restrict__ as2,
                                               const float* __restrict__ ad2,
                                               const int* __restrict__ rs,
                                               const int* __restrict__ esrc,
                                               const float* __restrict__ g,
                                               const float* __restrict__ b2,
                                               float* __restrict__ out) {
  int wave = threadIdx.x >> 6, lane = threadIdx.x & 63;
  int d = blockIdx.x * 4 + wave;
  if (d >= N2v) return;
  int beg = rs[d], end = rs[d + 1];
  float ad = ad2[d];
  float a_self = leaky(as2[d] + ad);
  float m = a_self;
  for (int p = beg; p < end; ++p) m = fmaxf(m, leaky(as2[esrc[p]] + ad));
  float ssum, acc;
  {
    float e = __expf(a_self - m);
    ssum = e;
    acc = (lane < NCLSv) ? e * g[(size_t)d * NCLSv + lane] : 0.f;
  }
  for (int p = beg; p < end; ++p) {
    int s = esrc[p];
    float e = __expf(leaky(as2[s] + ad) - m);
    ssum += e;
    if (lane < NCLSv) acc += e * g[(size_t)s * NCLSv + lane];
  }
  float logit = acc / ssum + ((lane < NCLSv) ? b2[lane] : 0.f);
  float v = (lane < NCLSv) ? logit : -INFINITY;
  float mx = v;
#pragma unroll
  for (int o = 32; o >= 1; o >>= 1) mx = fmaxf(mx, __shfl_xor(mx, o, 64));
  float p = (lane < NCLSv) ? __expf(v - mx) : 0.f;
  float sum = p;
#pragma unroll
  for (int o = 32; o >= 1; o >>= 1) sum += __shfl_xor(sum, o, 64);
  if (lane < NCLSv) out[(size_t)d * NCLSv + lane] = v - mx - logf(sum);
}

// ---------------- host launch: 6 dispatches ----------------
extern "C" void kernel_launch(void* const* d_in, const int* in_sizes, int n_in,
                              void* d_out, int out_size, void* d_ws, size_t ws_size,
                              hipStream_t stream) {
  const float* x = (const float*)d_in[0];
  const int* ei1 = (const int*)d_in[1];
  const int* ei2 = (const int*)d_in[2];
  const float* W1 = (const float*)d_in[5];
  const float* att_src1 = (const float*)d_in[6];
  const float* att_dst1 = (const float*)d_in[7];
  const float* b1 = (const float*)d_in[8];
  const float* W2 = (const float*)d_in[9];
  const float* att_src2 = (const float*)d_in[10];
  const float* att_dst2 = (const float*)d_in[11];
  const float* b2 = (const float*)d_in[12];
  float* out = (float*)d_out;

  const int E1 = in_sizes[1] / 2;
  const int E2 = in_sizes[2] / 2;
  const int* src1 = ei1;
  const int* dst1 = ei1 + E1;
  const int* src2 = ei2;
  const int* dst2 = ei2 + E2;

  char* w = (char*)d_ws;
  size_t off = 0;
  auto alloc = [&](size_t bytes) {
    void* p = w + off;
    off += (bytes + 255) & ~(size_t)255;
    return p;
  };
  unsigned short* Wt  = (unsigned short*)alloc((size_t)HCv * KPADv * 2);
  unsigned short* H   = (unsigned short*)alloc((size_t)N0v * HCv * 2);
  float* as1 = (float*)alloc((size_t)N0v * 8 * 4);
  float* ad1 = (float*)alloc((size_t)N1v * 8 * 4);
  int* deg1  = (int*)alloc((size_t)N1v * 4);
  int* rs1   = (int*)alloc((size_t)(N1v + 1) * 4);
  int* cur1  = (int*)alloc((size_t)N1v * 4);
  int* es1   = (int*)alloc((size_t)E1 * 4);
  float* g   = (float*)alloc((size_t)N1v * NCLSv * 4);
  float* as2 = (float*)alloc((size_t)N1v * 4);
  float* ad2 = (float*)alloc((size_t)N1v * 4);
  int* deg2  = (int*)alloc((size_t)N2v * 4);
  int* rs2   = (int*)alloc((size_t)(N2v + 1) * 4);
  int* cur2  = (int*)alloc((size_t)N2v * 4);
  int* es2   = (int*)alloc((size_t)E2 * 4);
  (void)ws_size; (void)n_in; (void)out_size;

  k_prep<<<(HCv * KPADv + 255) / 256, 256, 0, stream>>>(W1, Wt, deg1, deg2);
  k_gemm1<<<(N0v + 127) / 128, 512, 0, stream>>>(x, Wt, H, as1, ad1, att_src1, att_dst1,
                                                 dst1, E1, deg1, dst2, E2, deg2);
  k_scan2x<<<2, 1024, 0, stream>>>(deg1, rs1, cur1, N1v, deg2, rs2, cur2, N2v);
  k_scatter2x<<<(E1 + 255) / 256, 256, 0, stream>>>(src1, dst1, E1, cur1, es1,
                                                    src2, dst2, E2, cur2, es2);
  k_attn1f<<<(N1v + 3) / 4, 256, 0, stream>>>(as1, ad1, rs1, es1, H, b1,
                                              W2, att_src2, att_dst2, g, as2, ad2);
  k_attn2<<<N2v / 4, 256, 0, stream>>>(as2, ad2, rs2, es2, g, b2, out);
}